// Round 4
// baseline (727.669 us; speedup 1.0000x reference)
//
#include <hip/hip_runtime.h>
#include <cstdint>
#include <cstddef>

// ---------------------------------------------------------------------------
// TransformerMultiViewFusion (MI355X / gfx950), round 11.
//
//  R11 changes:
//   * ffn_fused_k reverted to R9 (measured 125us): 64-row tile, 2x16K
//     ping-pong, counted vmcnt, hc-rotation. R10's 128-row/1-blk-per-CU
//     variant regressed (147us): per-step time is latency-pinned (~2000cy)
//     and needs 2 co-resident blocks to overlap; traffic halving is
//     irrelevant (R7=R8, R10 worse with half the bytes).
//   * attention_k + gemm_ln_k fused into attn_ln_k: a 128-row Wo-GEMM block
//     = 32 sequences; attention computed per-wave in LDS (attention_k's
//     math, register-pipelined QKV loads), SA written directly into a
//     swizzled LDS A-tile, then gemm_ln's Wo GEMM + residual + LN.
//     Kills the SA workspace round-trip (75 MB/layer) + 1 launch/layer.
//     LDS: SAs 64K | {qf 48K -> Wo ping-pong 64K} | sc 2K | red 2K = 132K.
//
//  Workspace: X@0 | QKV@37748736 | Xf@188743680 | WpB@198180864 |
//             Wb@226492416  (SA slot unused)
// ---------------------------------------------------------------------------

typedef __bf16 bf16;
typedef __bf16 bf16x8 __attribute__((ext_vector_type(8)));
typedef __bf16 bf16x4 __attribute__((ext_vector_type(4)));
typedef float  f32x4  __attribute__((ext_vector_type(4)));

__device__ __forceinline__ void async_copy16(const void* g, void* l)
{
    __builtin_amdgcn_global_load_lds(
        (__attribute__((address_space(1))) void*)g,
        (__attribute__((address_space(3))) void*)l,
        16, 0, 0);
}

#define WAITV4_BAR() asm volatile("s_waitcnt vmcnt(4)\ns_barrier" ::: "memory")
#define WAITV0_BAR() asm volatile("s_waitcnt vmcnt(0)\ns_barrier" ::: "memory")
#define WAITL_BAR()  asm volatile("s_waitcnt lgkmcnt(0)\ns_barrier" ::: "memory")
#define WAITL()      asm volatile("s_waitcnt lgkmcnt(0)" ::: "memory")

// --------------------------------------------------------------------------
// all 5 weight packs in one launch. 1589248 = 6208*256 exactly.
// --------------------------------------------------------------------------
__global__ void pack_all_k(const float* __restrict__ s0, const float* __restrict__ s1,
                           const float* __restrict__ s2, const float* __restrict__ s3,
                           const float* __restrict__ s4,
                           bf16* __restrict__ d0, bf16* __restrict__ d1,
                           bf16* __restrict__ d2, bf16* __restrict__ d3,
                           bf16* __restrict__ d4)
{
    const int i = blockIdx.x * 256 + threadIdx.x;
    if (i < 393216)       d0[i] = (bf16)s0[i];
    else if (i < 524288)  d1[i - 393216] = (bf16)s1[i - 393216];
    else if (i < 1048576) d2[i - 524288] = (bf16)s2[i - 524288];
    else if (i < 1572864) d3[i - 1048576] = (bf16)s3[i - 1048576];
    else                  d4[i - 1572864] = (bf16)s4[i - 1572864];
}

// --------------------------------------------------------------------------
// feat transpose-pack: Xf[t][c] = (bf16)feat[cam][b][c][hw]
// --------------------------------------------------------------------------
__global__ __launch_bounds__(256) void feat_pack_k(const float* __restrict__ feat,
                                                   bf16* __restrict__ Xf)
{
    __shared__ float ft[64][68];

    const int tid  = threadIdx.x;
    const int camb = blockIdx.y;
    const int cam  = camb >> 1;
    const int b    = camb & 1;
    const int hw0  = blockIdx.x * 64;

    const float* fb = feat + (size_t)camb * 64 * 9216 + hw0;
#pragma unroll
    for (int rep = 0; rep < 16; ++rep) {
        const int idx = rep * 256 + tid;
        const int c = idx >> 6, p = idx & 63;
        ft[p][c] = fb[(size_t)c * 9216 + p];
    }
    __syncthreads();

    const int pbase = b * 9216 + hw0;
#pragma unroll
    for (int rep = 0; rep < 2; ++rep) {
        const int idx = rep * 256 + tid;
        const int p = idx >> 3, cc = idx & 7;
        const f32x4 a = *(const f32x4*)(&ft[p][cc * 8]);
        const f32x4 c4 = *(const f32x4*)(&ft[p][cc * 8 + 4]);
        bf16x8 v;
#pragma unroll
        for (int i = 0; i < 4; ++i) { v[i] = (bf16)a[i]; v[4 + i] = (bf16)c4[i]; }
        const size_t t = (size_t)(pbase + p) * 4 + cam;
        *(bf16x8*)(Xf + t * 64 + cc * 8) = v;
    }
}

// --------------------------------------------------------------------------
// GEMM-BT: C[M,N] = A[M,K] @ B[N,K]^T + bias[N], bf16 in/out. 128x128 tile.
// --------------------------------------------------------------------------
template <bool RELU>
__global__ __launch_bounds__(256, 2) void gemm_bt(
    const bf16* __restrict__ A, const bf16* __restrict__ B,
    const float* __restrict__ bias, bf16* __restrict__ C,
    int N, int K)
{
    __shared__ __align__(16) bf16 As[128 * 64];
    __shared__ __align__(16) bf16 Bs[128 * 64];

    const int tid  = threadIdx.x;
    const int lane = tid & 63;
    const int wv   = tid >> 6;
    const int wm   = wv >> 1;
    const int wn   = wv & 1;
    const int bm   = blockIdx.y * 128;
    const int bn   = blockIdx.x * 128;

    const int r8  = lane >> 3;
    const int p8  = lane & 7;
    const int gch = p8 ^ r8;

    const int quad = lane >> 4;
    const int l16  = lane & 15;

    f32x4 acc[4][4] = {};

    for (int k0 = 0; k0 < K; k0 += 64) {
#pragma unroll
        for (int inst = 0; inst < 4; ++inst) {
            const int row = wv * 32 + inst * 8 + r8;
            const bf16* ga = A + (size_t)(bm + row) * K + (k0 + gch * 8);
            const bf16* gb = B + (size_t)(bn + row) * K + (k0 + gch * 8);
            async_copy16(ga, (char*)As + (wv * 4 + inst) * 1024);
            async_copy16(gb, (char*)Bs + (wv * 4 + inst) * 1024);
        }
        __syncthreads();

#pragma unroll
        for (int kk = 0; kk < 2; ++kk) {
            bf16x8 af[4], bfr[4];
            const int lch = kk * 4 + quad;
#pragma unroll
            for (int i = 0; i < 4; ++i) {
                const int m = wm * 64 + i * 16 + l16;
                af[i] = *(const bf16x8*)((const char*)As + (m * 8 + (lch ^ (m & 7))) * 16);
                const int n = wn * 64 + i * 16 + l16;
                bfr[i] = *(const bf16x8*)((const char*)Bs + (n * 8 + (lch ^ (n & 7))) * 16);
            }
#pragma unroll
            for (int i = 0; i < 4; ++i)
#pragma unroll
                for (int j = 0; j < 4; ++j)
                    acc[i][j] = __builtin_amdgcn_mfma_f32_16x16x32_bf16(
                        af[i], bfr[j], acc[i][j], 0, 0, 0);
        }
        __syncthreads();
    }

#pragma unroll
    for (int j = 0; j < 4; ++j) {
        const int n = bn + wn * 64 + j * 16 + l16;
        const float bv = bias[n];
#pragma unroll
        for (int i = 0; i < 4; ++i) {
            const int mb = bm + wm * 64 + i * 16 + quad * 4;
#pragma unroll
            for (int r = 0; r < 4; ++r) {
                float v = acc[i][j][r] + bv;
                if (RELU) v = fmaxf(v, 0.f);
                C[(size_t)(mb + r) * N + n] = (bf16)v;
            }
        }
    }
}

// --------------------------------------------------------------------------
// Fused attention + Wo-GEMM + bias + residual + LayerNorm.
// Block = 128 rows = 32 sequences, 256 threads (4 waves).
// Phase 1: per-wave attention (8 iterations x 1 seq/wave), SA -> LDS A-tile
//          in ffn-Xs swizzle: chunk gc (0..31), slot=(gc&24)|((gc^m)&7).
// Phase 2: Wo GEMM from resident A-tile, B streamed 64-k chunks (ping-pong),
//          gemm_ln epilogue (residual + LN), in-place X.
// LDS: SAs 64K @0 | qf 48K / Bbuf 2x32K @64K | sc 2K @128K... laid out below.
// --------------------------------------------------------------------------
__global__ __launch_bounds__(256) void attn_ln_k(
    const bf16* __restrict__ QKV, const bf16* __restrict__ B,
    const float* __restrict__ bias, const bf16* __restrict__ Xres,
    const float* __restrict__ gam, const float* __restrict__ bet,
    bf16* __restrict__ Xout)
{
    __shared__ __align__(16) char smem[135168];
    bf16*  SAs  = (bf16*)smem;                       // 128 rows x 32 chunks
    char*  Bbuf = smem + 65536;                      // 2 x 32K (aliases qf)
    float* qf   = (float*)(smem + 65536);            // [4][4][768]
    float* sc   = (float*)(smem + 131072);           // [4][8][4][4]
    float2 (*red)[2] = (float2 (*)[2])(void*)(smem + 133120);  // [128][2]

    const int tid  = threadIdx.x;
    const int lane = tid & 63;
    const int wv   = tid >> 6;
    const int wm   = wv >> 1;
    const int wn   = wv & 1;
    const int quad = lane >> 4;
    const int l16  = lane & 15;
    const int bm   = blockIdx.x * 128;

    float* qf_w = qf + wv * 3072;
    float* sc_w = sc + wv * 128;

    // ================= phase 1: attention for 32 sequences =================
    {
        const int s0 = blockIdx.x * 32;
        bf16x8 nv[6];
        {
            const bf16* bse = QKV + (size_t)(s0 + wv) * 3072;
#pragma unroll
            for (int it = 0; it < 6; ++it)
                nv[it] = *(const bf16x8*)(bse + (it * 64 + lane) * 8);
        }
#pragma unroll
        for (int g = 0; g < 8; ++g) {
            // stage nv -> qf_w (f32)
#pragma unroll
            for (int it = 0; it < 6; ++it) {
                const int idx = it * 64 + lane;
                const int tok = idx / 96;
                const int e   = (idx % 96) * 8;
                f32x4 f0, f1;
#pragma unroll
                for (int i = 0; i < 4; ++i) {
                    f0[i] = (float)nv[it][i]; f1[i] = (float)nv[it][4 + i];
                }
                *(f32x4*)(qf_w + tok * 768 + e)     = f0;
                *(f32x4*)(qf_w + tok * 768 + e + 4) = f1;
            }
            // prefetch next seq group while computing this one
            bf16x8 nx[6];
            if (g < 7) {
                const bf16* bse = QKV + (size_t)(s0 + (g + 1) * 4 + wv) * 3072;
#pragma unroll
                for (int it = 0; it < 6; ++it)
                    nx[it] = *(const bf16x8*)(bse + (it * 64 + lane) * 8);
            }
            WAITL();   // qf_w writes complete (in-order DS per wave)

            // scores
#pragma unroll
            for (int rep = 0; rep < 2; ++rep) {
                const int t = rep * 64 + lane;
                const int h = t >> 4, i = (t >> 2) & 3, j = t & 3;
                const float* q = qf_w + i * 768 + h * 32;
                const float* k = qf_w + j * 768 + 256 + h * 32;
                float a = 0.f;
#pragma unroll
                for (int dd = 0; dd < 32; ++dd) {
                    const int d = (dd + lane) & 31;
                    a += q[d] * k[d];
                }
                sc_w[h * 16 + i * 4 + j] = a * 0.17677669529663687f;
            }
            WAITL();

            // softmax over 4 (lanes 0..31 handle the 32 (h,i) rows)
            if (lane < 32) {
                const int h = lane >> 2, i = lane & 3;
                float v0 = sc_w[h * 16 + i * 4 + 0];
                float v1 = sc_w[h * 16 + i * 4 + 1];
                float v2 = sc_w[h * 16 + i * 4 + 2];
                float v3 = sc_w[h * 16 + i * 4 + 3];
                const float m = fmaxf(fmaxf(v0, v1), fmaxf(v2, v3));
                const float e0 = expf(v0 - m), e1 = expf(v1 - m);
                const float e2 = expf(v2 - m), e3 = expf(v3 - m);
                const float inv = 1.f / (e0 + e1 + e2 + e3);
                sc_w[h * 16 + i * 4 + 0] = e0 * inv;
                sc_w[h * 16 + i * 4 + 1] = e1 * inv;
                sc_w[h * 16 + i * 4 + 2] = e2 * inv;
                sc_w[h * 16 + i * 4 + 3] = e3 * inv;
            }
            WAITL();

            // PV; write SA rows straight into swizzled A-tile
            const int h = lane >> 3;
#pragma unroll
            for (int i = 0; i < 4; ++i) {
                f32x4 a = {0.f, 0.f, 0.f, 0.f};
#pragma unroll
                for (int j = 0; j < 4; ++j) {
                    const float p = sc_w[h * 16 + i * 4 + j];
                    const f32x4 v = *(const f32x4*)(qf_w + j * 768 + 512 + lane * 4);
#pragma unroll
                    for (int q = 0; q < 4; ++q) a[q] += p * v[q];
                }
                bf16x4 o;
#pragma unroll
                for (int q = 0; q < 4; ++q) o[q] = (bf16)a[q];
                const int m  = (g * 4 + wv) * 4 + i;       // local row
                const int gc = lane >> 1;                  // 16B chunk (e/8)
                const int sl = (gc & 24) | ((gc ^ m) & 7);
                *(bf16x4*)((char*)SAs + (m * 32 + sl) * 16 + (lane & 1) * 8) = o;
            }
#pragma unroll
            for (int it = 0; it < 6; ++it) nv[it] = nx[it];
        }
    }
    __syncthreads();   // SAs complete; qf region reusable for B staging

    // ================= phase 2: Wo GEMM (K=256) =================
    f32x4 acc[4][8] = {};

#pragma unroll 1
    for (int c0 = 0; c0 < 4; ++c0) {
        char* buf = Bbuf + (size_t)(c0 & 1) * 32768;
#pragma unroll
        for (int it = 0; it < 8; ++it) {
            const int L   = it * 256 + tid;
            const int row = L >> 3;
            const int gch = (L & 7) ^ (row & 7);
            async_copy16(B + (size_t)row * 256 + (c0 * 64 + gch * 8),
                         buf + (size_t)L * 16);
        }
        __syncthreads();    // drains vmcnt -> B(c0) resident

#pragma unroll
        for (int kk = 0; kk < 2; ++kk) {
            const int lch = kk * 4 + quad;
            const int gc  = c0 * 8 + lch;
            bf16x8 af[4], bfr[8];
#pragma unroll
            for (int i = 0; i < 4; ++i) {
                const int m  = wm * 64 + i * 16 + l16;
                const int sl = (gc & 24) | ((gc ^ m) & 7);
                af[i] = *(const bf16x8*)((const char*)SAs + (m * 32 + sl) * 16);
            }
#pragma unroll
            for (int j = 0; j < 8; ++j) {
                const int n = wn * 128 + j * 16 + l16;
                bfr[j] = *(const bf16x8*)(buf + (n * 8 + (lch ^ (n & 7))) * 16);
            }
#pragma unroll
            for (int i = 0; i < 4; ++i)
#pragma unroll
                for (int j = 0; j < 8; ++j)
                    acc[i][j] = __builtin_amdgcn_mfma_f32_16x16x32_bf16(
                        af[i], bfr[j], acc[i][j], 0, 0, 0);
        }
        __syncthreads();    // reads done before next overwrite of other buf
    }

    // ---- epilogue: bias + residual + LayerNorm (gemm_ln's, verbatim)
    float bv[8], gv[8], bev[8];
#pragma unroll
    for (int j = 0; j < 8; ++j) {
        const int n = wn * 128 + j * 16 + l16;
        bv[j] = bias[n]; gv[j] = gam[n]; bev[j] = bet[n];
    }

#pragma unroll
    for (int i = 0; i < 4; ++i) {
#pragma unroll
        for (int r = 0; r < 4; ++r) {
            const int rl  = wm * 64 + i * 16 + quad * 4 + r;
            const size_t row = (size_t)(bm + rl);
            float s1 = 0.f, s2 = 0.f;
#pragma unroll
            for (int j = 0; j < 8; ++j) {
                const int n = wn * 128 + j * 16 + l16;
                const float v = acc[i][j][r] + bv[j] + (float)Xres[row * 256 + n];
                acc[i][j][r] = v;
                s1 += v; s2 += v * v;
            }
#pragma unroll
            for (int off = 1; off < 16; off <<= 1) {
                s1 += __shfl_xor(s1, off, 64);
                s2 += __shfl_xor(s2, off, 64);
            }
            if (l16 == 0) red[rl][wn] = make_float2(s1, s2);
        }
    }
    __syncthreads();

#pragma unroll
    for (int i = 0; i < 4; ++i) {
#pragma unroll
        for (int r = 0; r < 4; ++r) {
            const int rl = wm * 64 + i * 16 + quad * 4 + r;
            const float2 p0 = red[rl][0], p1 = red[rl][1];
            const float mu  = (p0.x + p1.x) * (1.f / 256.f);
            const float ex2 = (p0.y + p1.y) * (1.f / 256.f);
            const float rstd = rsqrtf(fmaxf(ex2 - mu * mu, 0.f) + 1e-5f);
            const size_t row = (size_t)(bm + rl);
#pragma unroll
            for (int j = 0; j < 8; ++j) {
                const int n = wn * 128 + j * 16 + l16;
                Xout[row * 256 + n] = (bf16)((acc[i][j][r] - mu) * rstd * gv[j] + bev[j]);
            }
        }
    }
}

// --------------------------------------------------------------------------
// ffn stage step s (0..63) with per-block hc rotation: hc = ((s>>3)+rot)&7.
//  q<4 : W1 quarter  [128 h][64 k]  8 chunks/row, slot = c ^ (row&7)
//  q>=4: W2 quarter  [256 n][32 k]  paired rows: LDS row = n>>1, 8 slots =
//        ((n&1)*4 + c) ^ ((n>>1)&7)  -> fragment reads 2-way (free)
// --------------------------------------------------------------------------
__device__ __forceinline__ void ffn_stage(int s, int rot, const bf16* __restrict__ W1,
                                          const bf16* __restrict__ W2,
                                          char* buf, int tid)
{
    const int hc = ((s >> 3) + rot) & 7;
    const int q  = s & 7;
    if (q < 4) {
#pragma unroll
        for (int it = 0; it < 4; ++it) {
            const int L = it * 256 + tid;
            const int row = L >> 3, psl = L & 7;
            const int c = psl ^ (row & 7);
            async_copy16(W1 + (size_t)(hc * 128 + row) * 256 + q * 64 + c * 8,
                         buf + (size_t)L * 16);
        }
    } else {
#pragma unroll
        for (int it = 0; it < 4; ++it) {
            const int L = it * 256 + tid;
            const int r128 = L >> 3, psl = L & 7;
            const int g = psl ^ (r128 & 7);
            const int n = r128 * 2 + (g >> 2);
            const int c = g & 3;
            async_copy16(W2 + (size_t)n * 1024 + hc * 128 + (q - 4) * 32 + c * 8,
                         buf + (size_t)L * 16);
        }
    }
}

// --------------------------------------------------------------------------
// Fused FFN (R9): Xout = LN(X + relu(X@W1^T+b1)@W2^T + b2)*gam + bet.
// 64-row tile, grid 1152, 4 waves 2x2. 8 hidden chunks of 128, rotated per
// block (L2 de-phasing). Counted-vmcnt ping-pong: stage(s+1) in flight
// across both barriers of step s.
// LDS: Xs 32K | Ts 16K (red aliases) | stage 2x16K = 80KB -> 2 blocks/CU.
// --------------------------------------------------------------------------
__global__ __launch_bounds__(256, 2) void ffn_fused_k(
    const bf16* __restrict__ X,
    const bf16* __restrict__ W1, const float* __restrict__ b1,
    const bf16* __restrict__ W2, const float* __restrict__ b2,
    const float* __restrict__ gam, const float* __restrict__ bet,
    bf16* __restrict__ Xout)
{
    __shared__ __align__(16) char smem[81920];
    bf16* Xs = (bf16*)smem;                       // 64 x 256 (32 slots/row)
    bf16* Ts = (bf16*)(smem + 32768);             // 64 x 128 (16 slots/row)
    float2 (*red)[2] = (float2 (*)[2])(void*)(smem + 32768);   // aliases Ts
    char* stg = smem + 49152;                     // 2 x 16KB

    const int tid  = threadIdx.x;
    const int lane = tid & 63;
    const int wv   = tid >> 6;
    const int wm   = wv >> 1;
    const int wn   = wv & 1;
    const int quad = lane >> 4;
    const int l16  = lane & 15;
    const int bm   = blockIdx.x * 64;
    const int rot  = (blockIdx.x >> 3) & 7;

#pragma unroll
    for (int it = 0; it < 8; ++it) {
        const int L = it * 256 + tid;
        const int row = L >> 5, slot = L & 31;
        const int gch = (slot & 24) | ((slot ^ row) & 7);
        async_copy16(X + (size_t)(bm + row) * 256 + gch * 8,
                     (char*)Xs + (size_t)L * 16);
    }
    ffn_stage(0, rot, W1, W2, stg, tid);
    ffn_stage(1, rot, W1, W2, stg + 16384, tid);

    f32x4 acc2[2][8] = {};

#pragma unroll 1
    for (int hc = 0; hc < 8; ++hc) {
        const int hcr = (hc + rot) & 7;
        float b1v[4];
#pragma unroll
        for (int j = 0; j < 4; ++j)
            b1v[j] = b1[hcr * 128 + wn * 64 + j * 16 + l16];

        f32x4 accA[2][4] = {};

        // ---- phase A: accA = Xs @ W1c^T, 4 steps of 64k
#pragma unroll
        for (int q = 0; q < 4; ++q) {
            const int s = hc * 8 + q;
            const char* cur = stg + (size_t)(q & 1) * 16384;
            ffn_stage(s + 1, rot, W1, W2, stg + (size_t)((q + 1) & 1) * 16384, tid);
            WAITV4_BAR();
#pragma unroll
            for (int kk = 0; kk < 2; ++kk) {
                const int ch = kk * 4 + quad;
                const int gc = q * 8 + ch;
                bf16x8 af[2], bfr[4];
#pragma unroll
                for (int i = 0; i < 2; ++i) {
                    const int m  = wm * 32 + i * 16 + l16;
                    const int sl = (gc & 24) | ((gc ^ m) & 7);
                    af[i] = *(const bf16x8*)((const char*)Xs + (m * 32 + sl) * 16);
                }
#pragma unroll
                for (int j = 0; j < 4; ++j) {
                    const int n  = wn * 64 + j * 16 + l16;
                    const int sl = ch ^ (n & 7);
                    bfr[j] = *(const bf16x8*)(cur + (n * 8 + sl) * 16);
                }
                __builtin_amdgcn_s_setprio(1);
#pragma unroll
                for (int i = 0; i < 2; ++i)
#pragma unroll
                    for (int j = 0; j < 4; ++j)
                        accA[i][j] = __builtin_amdgcn_mfma_f32_16x16x32_bf16(
                            af[i], bfr[j], accA[i][j], 0, 0, 0);
                __builtin_amdgcn_s_setprio(0);
            }
            WAITL_BAR();
        }

        // ---- Ts = relu(accA + b1)
#pragma unroll
        for (int j = 0; j < 4; ++j) {
            const int h  = wn * 64 + j * 16 + l16;
            const float bb = b1v[j];
            const int g  = h >> 3;
#pragma unroll
            for (int i = 0; i < 2; ++i)
#pragma unroll
                for (int r = 0; r < 4; ++r) {
                    const int m  = wm * 32 + i * 16 + quad * 4 + r;
                    const int sl = (g & 8) | ((g ^ m) & 7);
                    const float v = fmaxf(accA[i][j][r] + bb, 0.f);
                    *((bf16*)((char*)Ts + (m * 16 + sl) * 16 + (h & 7) * 2)) = (bf16)v;
                }
        }
        WAITL_BAR();

        // ---- phase B: acc2 += Ts @ W2c^T, 4 steps of 32k
#pragma unroll
        for (int q = 0; q < 4; ++q) {
            const int s = hc * 8 + 4 + q;
            const char* cur = stg + (size_t)(q & 1) * 16384;
            if (s < 63) {
                ffn_stage(s + 1, rot, W1, W2, stg + (size_t)((q + 1) & 1) * 16384, tid);
                WAITV4_BAR();
            } else {
                WAITV0_BAR();
            }
            const int tc = q * 4 + quad;
            bf16x8 af[2], bfr[8];
#pragma unroll
            for (int i = 0; i < 2; ++i) {
                const int m  = wm * 32 + i * 16 + l16;
                const int sl = (tc & 8) | ((tc ^ m) & 7);
                af[i] = *(const bf16x8*)((const char*)Ts + (m * 16 + sl) * 16);
            }
#pragma unroll
            for (int j = 0; j < 8; ++j) {
                const int n  = wn * 128 + j * 16 + l16;
                const int sl = (((n & 1) * 4 + quad) ^ ((n >> 1) & 7)) & 7;
                bfr[j] = *(const bf16x8*)(cur + ((n >> 1) * 8 + sl) * 16);
            }
            __builtin_amdgcn_s_setprio(1);
#pragma unroll
            for (int i = 0; i < 2; ++i)
#pragma unroll
                for (int j = 0; j < 8; ++j)
                    acc2[i][j] = __builtin_amdgcn_mfma_f32_16x16x32_bf16(
                        af[i], bfr[j], acc2[i][j], 0, 0, 0);
            __builtin_amdgcn_s_setprio(0);
            WAITL_BAR();
        }
    }

    // ---- epilogue: bias + residual (from Xs) + LayerNorm
    float bv[8], gv[8], bev[8];
#pragma unroll
    for (int j = 0; j < 8; ++j) {
        const int n = wn * 128 + j * 16 + l16;
        bv[j] = b2[n]; gv[j] = gam[n]; bev[j] = bet[n];
    }

#pragma unroll
    for (int i = 0; i < 2; ++i) {
#pragma unroll
        for (int r = 0; r < 4; ++r) {
            const int rl = wm * 32 + i * 16 + quad * 4 + r;
            float s1 = 0.f, s2 = 0.f;
#pragma unroll
            for (int j = 0; j < 8; ++j) {
                const int n  = wn * 128 + j * 16 + l16;
                const int gc = n >> 3;
                const int sl = (gc & 24) | ((gc ^ rl) & 7);
                const float xr = (float)*((const bf16*)((const char*)Xs +
                                   (rl * 32 + sl) * 16 + (n & 7) * 2));
                const float v = acc2[i][j][r] + bv[j] + xr;
                acc2[i][j][r] = v;
                s1 += v; s2 += v * v;
            }
#pragma unroll
            for (int off = 1; off < 16; off <<= 1) {
                s1 += __shfl_xor(s1, off, 64);
                s2 += __shfl_xor(s2, off, 64);
            }
            if (l16 == 0) red[rl][wn] = make_float2(s1, s2);
        }
    }
    __syncthreads();

#pragma unroll
    for (int i = 0; i < 2; ++i) {
#pragma unroll
        for (int r = 0; r < 4; ++r) {
            const int rl = wm * 32 + i * 16 + quad * 4 + r;
            const float2 p0 = red[rl][0], p1 = red[rl][1];
            const float mu  = (p0.x + p1.x) * (1.f / 256.f);
            const float ex2 = (p0.y + p1.y) * (1.f / 256.f);
            const float rstd = rsqrtf(fmaxf(ex2 - mu * mu, 0.f) + 1e-5f);
            const size_t row = (size_t)(bm + rl);
#pragma unroll
            for (int j = 0; j < 8; ++j) {
                const int n = wn * 128 + j * 16 + l16;
                Xout[row * 256 + n] = (bf16)((acc2[i][j][r] - mu) * rstd * gv[j] + bev[j]);
            }
        }
    }
}

// --------------------------------------------------------------------------
// out[b][c][hw] = sum_e (mean_cam X[p*4+cam][e]) * Wout[c][e] + bout[c]
// --------------------------------------------------------------------------
__global__ __launch_bounds__(256) void out_proj_k(const bf16* __restrict__ X,
                                                  const float* __restrict__ Wout,
                                                  const float* __restrict__ bout,
                                                  float* __restrict__ out)
{
    __shared__ float fused[16][260];
    const int tid = threadIdx.x;
    const int p0  = blockIdx.x * 16;

#pragma unroll
    for (int it = 0; it < 16; ++it) {
        const int idx = it * 256 + tid;
        const int pix = idx >> 8, e = idx & 255;
        const size_t base = (size_t)(p0 + pix) * 1024 + e;
        const float s = (float)X[base] + (float)X[base + 256] +
                        (float)X[base + 512] + (float)X[base + 768];
        fused[pix][e] = s * 0.25f;
    }
    __syncthreads();

    const int pix = tid & 15;
    const int c0  = tid >> 4;
    const int p   = p0 + pix;
    const int b   = p / 9216;
    const int hw  = p % 9216;
#pragma unroll
    for (int it = 0; it < 4; ++it) {
        const int c = it * 16 + c0;
        const float* w = Wout + c * 256;
        float acc = bout[c];
#pragma unroll 8
        for (int e = 0; e < 256; ++e) acc += fused[pix][e] * w[e];
        out[((size_t)b * 64 + c) * 9216 + hw] = acc;
    }
}

// --------------------------------------------------------------------------
extern "C" void kernel_launch(void* const* d_in, const int* in_sizes, int n_in,
                              void* d_out, int out_size, void* d_ws, size_t ws_size,
                              hipStream_t stream)
{
    const float* features = (const float*)d_in[0];
    const float* Wp   = (const float*)d_in[1];
    const float* bp   = (const float*)d_in[2];
    const float* Wqkv = (const float*)d_in[3];
    const float* bqkv = (const float*)d_in[4];
    const float* Wo   = (const float*)d_in[5];
    const float* bo   = (const float*)d_in[6];
    const float* W1   = (const float*)d_in[7];
    const float* b1   = (const float*)d_in[8];
    const float* W2   = (const float*)d_in[9];
    const float* b2   = (const float*)d_in[10];
    const float* g1   = (const float*)d_in[11];
    const float* be1  = (const float*)d_in[12];
    const float* g2   = (const float*)d_in[13];
    const float* be2  = (const float*)d_in[14];
    const float* Wout = (const float*)d_in[15];
    const float* bout = (const float*)d_in[16];
    float* out = (float*)d_out;

    char* ws = (char*)d_ws;
    bf16* X   = (bf16*)(ws);                    // 73728*256
    bf16* QKV = (bf16*)(ws + 37748736ull);      // 73728*768
    bf16* Xf  = (bf16*)(ws + 188743680ull);     // 73728*64
    bf16* WpB = (bf16*)(ws + 198180864ull);     // 256*64
    bf16* Wb  = (bf16*)(ws + 226492416ull);     // packed bf16 weights

    bf16* WqkvB = Wb;                  // 2 x 768*256
    bf16* WoB   = Wb + 393216;         // 2 x 256*256
    bf16* W1B   = Wb + 524288;         // 2 x 1024*256
    bf16* W2B   = Wb + 1048576;        // 2 x 256*1024

    pack_all_k<<<6208, 256, 0, stream>>>(Wqkv, Wo, W1, W2, Wp,
                                         WqkvB, WoB, W1B, W2B, WpB);

    feat_pack_k<<<dim3(144, 8), 256, 0, stream>>>(features, Xf);
    gemm_bt<false><<<dim3(2, 576), 256, 0, stream>>>(Xf, WpB, bp, X, 256, 64);

    for (int l = 0; l < 2; ++l) {
        gemm_bt<false><<<dim3(6, 576), 256, 0, stream>>>(
            X, WqkvB + l * 196608, bqkv + l * 768, QKV, 768, 256);
        attn_ln_k<<<576, 256, 0, stream>>>(
            QKV, WoB + l * 65536, bo + l * 256, X,
            g1 + l * 256, be1 + l * 256, X);
        ffn_fused_k<<<1152, 256, 0, stream>>>(
            X, W1B + l * 262144, b1 + l * 1024,
            W2B + l * 262144, b2 + l * 256,
            g2 + l * 256, be2 + l * 256, X);
    }

    out_proj_k<<<1152, 256, 0, stream>>>(X, Wout, bout, out);
}

// Round 5
// 603.206 us; speedup vs baseline: 1.2063x; 1.2063x over previous
//
#include <hip/hip_runtime.h>
#include <cstdint>
#include <cstddef>

// ---------------------------------------------------------------------------
// TransformerMultiViewFusion (MI355X / gfx950), round 12.
//
//  R12 changes:
//   * attn_ln_k v2: register-resident attention (no LDS, no WAITL chains) +
//     64-row tile -> 66.5KB LDS -> 2 blocks/CU (R11 was 1 blk/CU, 1 wave/SIMD,
//     latency-dead: MfmaUtil 2%). Lane=(head,colgroup) holds q/k/v[4][4] in
//     regs; scores via 3x shfl_xor in 8-lane head groups; redundant softmax;
//     PV in regs; bf16x4 straight into swizzled SAs. Phase 2 = ffn phase-B
//     verbatim: 8 k-steps of 32, paired-row Wo staging, counted vmcnt(4)
//     ping-pong, setprio. Epilogue = ffn epilogue w/ global residual.
//   * gemm_bt v2: counted-vmcnt double-buffer (ffn pattern): stage(k+1) in
//     flight across the barrier, vmcnt(8), no full drains inside the K loop.
//   * ffn_fused_k: unchanged R9 structure (banked 125us).
//
//  Workspace: X@0 | QKV@37748736 | Xf@188743680 | WpB@198180864 |
//             Wb@226492416
// ---------------------------------------------------------------------------

typedef __bf16 bf16;
typedef __bf16 bf16x8 __attribute__((ext_vector_type(8)));
typedef __bf16 bf16x4 __attribute__((ext_vector_type(4)));
typedef float  f32x4  __attribute__((ext_vector_type(4)));

__device__ __forceinline__ void async_copy16(const void* g, void* l)
{
    __builtin_amdgcn_global_load_lds(
        (__attribute__((address_space(1))) void*)g,
        (__attribute__((address_space(3))) void*)l,
        16, 0, 0);
}

#define WAITV8_BAR() asm volatile("s_waitcnt vmcnt(8)\ns_barrier" ::: "memory")
#define WAITV4_BAR() asm volatile("s_waitcnt vmcnt(4)\ns_barrier" ::: "memory")
#define WAITV0_BAR() asm volatile("s_waitcnt vmcnt(0)\ns_barrier" ::: "memory")
#define WAITL_BAR()  asm volatile("s_waitcnt lgkmcnt(0)\ns_barrier" ::: "memory")

// --------------------------------------------------------------------------
// all 5 weight packs in one launch. 1589248 = 6208*256 exactly.
// --------------------------------------------------------------------------
__global__ void pack_all_k(const float* __restrict__ s0, const float* __restrict__ s1,
                           const float* __restrict__ s2, const float* __restrict__ s3,
                           const float* __restrict__ s4,
                           bf16* __restrict__ d0, bf16* __restrict__ d1,
                           bf16* __restrict__ d2, bf16* __restrict__ d3,
                           bf16* __restrict__ d4)
{
    const int i = blockIdx.x * 256 + threadIdx.x;
    if (i < 393216)       d0[i] = (bf16)s0[i];
    else if (i < 524288)  d1[i - 393216] = (bf16)s1[i - 393216];
    else if (i < 1048576) d2[i - 524288] = (bf16)s2[i - 524288];
    else if (i < 1572864) d3[i - 1048576] = (bf16)s3[i - 1048576];
    else                  d4[i - 1572864] = (bf16)s4[i - 1572864];
}

// --------------------------------------------------------------------------
// feat transpose-pack: Xf[t][c] = (bf16)feat[cam][b][c][hw]
// --------------------------------------------------------------------------
__global__ __launch_bounds__(256) void feat_pack_k(const float* __restrict__ feat,
                                                   bf16* __restrict__ Xf)
{
    __shared__ float ft[64][68];

    const int tid  = threadIdx.x;
    const int camb = blockIdx.y;
    const int cam  = camb >> 1;
    const int b    = camb & 1;
    const int hw0  = blockIdx.x * 64;

    const float* fb = feat + (size_t)camb * 64 * 9216 + hw0;
#pragma unroll
    for (int rep = 0; rep < 16; ++rep) {
        const int idx = rep * 256 + tid;
        const int c = idx >> 6, p = idx & 63;
        ft[p][c] = fb[(size_t)c * 9216 + p];
    }
    __syncthreads();

    const int pbase = b * 9216 + hw0;
#pragma unroll
    for (int rep = 0; rep < 2; ++rep) {
        const int idx = rep * 256 + tid;
        const int p = idx >> 3, cc = idx & 7;
        const f32x4 a = *(const f32x4*)(&ft[p][cc * 8]);
        const f32x4 c4 = *(const f32x4*)(&ft[p][cc * 8 + 4]);
        bf16x8 v;
#pragma unroll
        for (int i = 0; i < 4; ++i) { v[i] = (bf16)a[i]; v[4 + i] = (bf16)c4[i]; }
        const size_t t = (size_t)(pbase + p) * 4 + cam;
        *(bf16x8*)(Xf + t * 64 + cc * 8) = v;
    }
}

// --------------------------------------------------------------------------
// GEMM-BT v2: C[M,N] = A[M,K] @ B[N,K]^T + bias[N]. 128x128 tile, counted
// vmcnt ping-pong (K-step 64): stage(k+1) in flight across the barrier.
// LDS 2 x (As 16K | Bs 16K) = 64K -> 2 blocks/CU.
// --------------------------------------------------------------------------
template <bool RELU>
__global__ __launch_bounds__(256, 2) void gemm_bt(
    const bf16* __restrict__ A, const bf16* __restrict__ B,
    const float* __restrict__ bias, bf16* __restrict__ C,
    int N, int K)
{
    __shared__ __align__(16) char smem[65536];

    const int tid  = threadIdx.x;
    const int lane = tid & 63;
    const int wv   = tid >> 6;
    const int wm   = wv >> 1;
    const int wn   = wv & 1;
    const int bm   = blockIdx.y * 128;
    const int bn   = blockIdx.x * 128;

    const int r8  = lane >> 3;
    const int p8  = lane & 7;
    const int gch = p8 ^ r8;

    const int quad = lane >> 4;
    const int l16  = lane & 15;

    f32x4 acc[4][4] = {};
    const int nk = K >> 6;

    auto STAGE = [&](int kc, char* base) {
#pragma unroll
        for (int inst = 0; inst < 4; ++inst) {
            const int row = wv * 32 + inst * 8 + r8;
            async_copy16(A + (size_t)(bm + row) * K + (kc * 64 + gch * 8),
                         base + (wv * 4 + inst) * 1024);
            async_copy16(B + (size_t)(bn + row) * K + (kc * 64 + gch * 8),
                         base + 16384 + (wv * 4 + inst) * 1024);
        }
    };

    STAGE(0, smem);

#pragma unroll 1
    for (int kc = 0; kc < nk; ++kc) {
        const char* cur = smem + (size_t)(kc & 1) * 32768;
        if (kc + 1 < nk) {
            STAGE(kc + 1, smem + (size_t)((kc + 1) & 1) * 32768);
            WAITV8_BAR();
        } else {
            WAITV0_BAR();
        }

#pragma unroll
        for (int kk = 0; kk < 2; ++kk) {
            bf16x8 af[4], bfr[4];
            const int lch = kk * 4 + quad;
#pragma unroll
            for (int i = 0; i < 4; ++i) {
                const int m = wm * 64 + i * 16 + l16;
                af[i] = *(const bf16x8*)(cur + (m * 8 + (lch ^ (m & 7))) * 16);
                const int n = wn * 64 + i * 16 + l16;
                bfr[i] = *(const bf16x8*)(cur + 16384 + (n * 8 + (lch ^ (n & 7))) * 16);
            }
            __builtin_amdgcn_s_setprio(1);
#pragma unroll
            for (int i = 0; i < 4; ++i)
#pragma unroll
                for (int j = 0; j < 4; ++j)
                    acc[i][j] = __builtin_amdgcn_mfma_f32_16x16x32_bf16(
                        af[i], bfr[j], acc[i][j], 0, 0, 0);
            __builtin_amdgcn_s_setprio(0);
        }
        WAITL_BAR();
    }

#pragma unroll
    for (int j = 0; j < 4; ++j) {
        const int n = bn + wn * 64 + j * 16 + l16;
        const float bv = bias[n];
#pragma unroll
        for (int i = 0; i < 4; ++i) {
            const int mb = bm + wm * 64 + i * 16 + quad * 4;
#pragma unroll
            for (int r = 0; r < 4; ++r) {
                float v = acc[i][j][r] + bv;
                if (RELU) v = fmaxf(v, 0.f);
                C[(size_t)(mb + r) * N + n] = (bf16)v;
            }
        }
    }
}

// --------------------------------------------------------------------------
// Wo stage: 16KB chunk [256 n][32 k] in paired-row layout (ffn W2 pattern):
// LDS row = n>>1, slot = ((n&1)*4 + c) ^ ((n>>1)&7). 4 instr/thread.
// --------------------------------------------------------------------------
__device__ __forceinline__ void wo_stage(const bf16* __restrict__ Wo, int kc,
                                         char* buf, int tid)
{
#pragma unroll
    for (int it = 0; it < 4; ++it) {
        const int L = it * 256 + tid;
        const int r128 = L >> 3, psl = L & 7;
        const int g = psl ^ (r128 & 7);
        const int n = r128 * 2 + (g >> 2);
        const int c = g & 3;
        async_copy16(Wo + (size_t)n * 256 + kc * 32 + c * 8,
                     buf + (size_t)L * 16);
    }
}

// --------------------------------------------------------------------------
// Fused attention + Wo-GEMM + bias + residual + LayerNorm. v2.
// Block = 64 rows = 16 sequences, 256 threads (4 waves), 2 blocks/CU.
// Phase 1: register attention. lane = (head h=lane>>3, colgrp c=lane&7).
//   Per seq: q/k/v[4 tok][4 cols] in regs; score partials + shfl_xor(1,2,4)
//   reduce within the 8-lane head group; redundant softmax; PV in regs;
//   bf16x4 -> swizzled SAs (ffn-Xs layout: chunk gc, slot=(gc&24)|((gc^m)&7)).
// Phase 2: ffn phase-B: 8 k-steps of 32, counted vmcnt(4) ping-pong Wo.
// LDS: SAs 32K | Wo 2x16K | red 1K = 66.5K.
// --------------------------------------------------------------------------
__global__ __launch_bounds__(256, 2) void attn_ln_k(
    const bf16* __restrict__ QKV, const bf16* __restrict__ Wo,
    const float* __restrict__ bias, const bf16* __restrict__ Xres,
    const float* __restrict__ gam, const float* __restrict__ bet,
    bf16* __restrict__ Xout)
{
    __shared__ __align__(16) char smem[66560];
    bf16* SAs  = (bf16*)smem;                     // 64 rows x 32 chunks (32K)
    char* Bbuf = smem + 32768;                    // 2 x 16K
    float2 (*red)[2] = (float2 (*)[2])(void*)(smem + 65536);   // [64][2]

    const int tid  = threadIdx.x;
    const int lane = tid & 63;
    const int wv   = tid >> 6;
    const int wm   = wv >> 1;
    const int wn   = wv & 1;
    const int quad = lane >> 4;
    const int l16  = lane & 15;
    const int bm   = blockIdx.x * 64;

    // prefetch Wo k-chunk 0 while attention runs
    wo_stage(Wo, 0, Bbuf, tid);

    // ================= phase 1: register attention, 4 seqs/wave ============
    {
        const int hh = lane >> 3;        // head 0..7
        const int cg = lane & 7;         // 4-col group 0..7 (cols cg*4..+3)
        const int s0 = blockIdx.x * 16;
        const float SCALE = 0.17677669529663687f;

#pragma unroll
        for (int g = 0; g < 4; ++g) {
            const int seq = s0 + g * 4 + wv;
            const bf16* bse = QKV + (size_t)seq * 3072 + hh * 32 + cg * 4;

            float qf[4][4], kf[4][4], vf[4][4];
#pragma unroll
            for (int i = 0; i < 4; ++i) {
                const bf16x4 qb = *(const bf16x4*)(bse + i * 768);
                const bf16x4 kb = *(const bf16x4*)(bse + i * 768 + 256);
                const bf16x4 vb = *(const bf16x4*)(bse + i * 768 + 512);
#pragma unroll
                for (int d = 0; d < 4; ++d) {
                    qf[i][d] = (float)qb[d];
                    kf[i][d] = (float)kb[d];
                    vf[i][d] = (float)vb[d];
                }
            }

            float sc[4][4];
#pragma unroll
            for (int i = 0; i < 4; ++i)
#pragma unroll
                for (int j = 0; j < 4; ++j)
                    sc[i][j] = qf[i][0] * kf[j][0] + qf[i][1] * kf[j][1]
                             + qf[i][2] * kf[j][2] + qf[i][3] * kf[j][3];

            // complete dot products across the 8-lane head group
#pragma unroll
            for (int msk = 1; msk <= 4; msk <<= 1)
#pragma unroll
                for (int i = 0; i < 4; ++i)
#pragma unroll
                    for (int j = 0; j < 4; ++j)
                        sc[i][j] += __shfl_xor(sc[i][j], msk, 64);

            // softmax per row (redundant across the 8 lanes)
#pragma unroll
            for (int i = 0; i < 4; ++i) {
                const float v0 = sc[i][0] * SCALE, v1 = sc[i][1] * SCALE;
                const float v2 = sc[i][2] * SCALE, v3 = sc[i][3] * SCALE;
                const float mx = fmaxf(fmaxf(v0, v1), fmaxf(v2, v3));
                const float e0 = expf(v0 - mx), e1 = expf(v1 - mx);
                const float e2 = expf(v2 - mx), e3 = expf(v3 - mx);
                const float inv = 1.f / (e0 + e1 + e2 + e3);
                sc[i][0] = e0 * inv; sc[i][1] = e1 * inv;
                sc[i][2] = e2 * inv; sc[i][3] = e3 * inv;
            }

            // PV + store to swizzled SAs
#pragma unroll
            for (int i = 0; i < 4; ++i) {
                bf16x4 ov;
#pragma unroll
                for (int d = 0; d < 4; ++d) {
                    const float o = sc[i][0] * vf[0][d] + sc[i][1] * vf[1][d]
                                  + sc[i][2] * vf[2][d] + sc[i][3] * vf[3][d];
                    ov[d] = (bf16)o;
                }
                const int m  = (g * 4 + wv) * 4 + i;
                const int gc = lane >> 1;
                const int sl = (gc & 24) | ((gc ^ m) & 7);
                *(bf16x4*)((char*)SAs + (m * 32 + sl) * 16 + (lane & 1) * 8) = ov;
            }
        }
    }
    __syncthreads();   // SAs complete (drains stage(0) too — already landed)

    // ================= phase 2: Wo GEMM, 8 k-steps of 32 ===================
    f32x4 acc[2][8] = {};

#pragma unroll
    for (int s = 0; s < 8; ++s) {
        const char* cur = Bbuf + (size_t)(s & 1) * 16384;
        if (s < 7) {
            wo_stage(Wo, s + 1, Bbuf + (size_t)((s + 1) & 1) * 16384, tid);
            WAITV4_BAR();
        } else {
            WAITV0_BAR();
        }
        const int gc = s * 4 + quad;          // SAs k-chunk 0..31
        bf16x8 af[2], bfr[8];
#pragma unroll
        for (int i = 0; i < 2; ++i) {
            const int m  = wm * 32 + i * 16 + l16;
            const int sl = (gc & 24) | ((gc ^ m) & 7);
            af[i] = *(const bf16x8*)((const char*)SAs + (m * 32 + sl) * 16);
        }
#pragma unroll
        for (int j = 0; j < 8; ++j) {
            const int n  = wn * 128 + j * 16 + l16;
            const int sl = (((n & 1) * 4 + quad) ^ ((n >> 1) & 7)) & 7;
            bfr[j] = *(const bf16x8*)(cur + ((n >> 1) * 8 + sl) * 16);
        }
        __builtin_amdgcn_s_setprio(1);
#pragma unroll
        for (int i = 0; i < 2; ++i)
#pragma unroll
            for (int j = 0; j < 8; ++j)
                acc[i][j] = __builtin_amdgcn_mfma_f32_16x16x32_bf16(
                    af[i], bfr[j], acc[i][j], 0, 0, 0);
        __builtin_amdgcn_s_setprio(0);
        WAITL_BAR();
    }

    // ---- epilogue: bias + residual (global) + LayerNorm
    float bv[8], gv[8], bev[8];
#pragma unroll
    for (int j = 0; j < 8; ++j) {
        const int n = wn * 128 + j * 16 + l16;
        bv[j] = bias[n]; gv[j] = gam[n]; bev[j] = bet[n];
    }

#pragma unroll
    for (int i = 0; i < 2; ++i) {
#pragma unroll
        for (int r = 0; r < 4; ++r) {
            const int rl = wm * 32 + i * 16 + quad * 4 + r;
            const size_t row = (size_t)(bm + rl);
            float s1 = 0.f, s2 = 0.f;
#pragma unroll
            for (int j = 0; j < 8; ++j) {
                const int n = wn * 128 + j * 16 + l16;
                const float v = acc[i][j][r] + bv[j] + (float)Xres[row * 256 + n];
                acc[i][j][r] = v;
                s1 += v; s2 += v * v;
            }
#pragma unroll
            for (int off = 1; off < 16; off <<= 1) {
                s1 += __shfl_xor(s1, off, 64);
                s2 += __shfl_xor(s2, off, 64);
            }
            if (l16 == 0) red[rl][wn] = make_float2(s1, s2);
        }
    }
    __syncthreads();

#pragma unroll
    for (int i = 0; i < 2; ++i) {
#pragma unroll
        for (int r = 0; r < 4; ++r) {
            const int rl = wm * 32 + i * 16 + quad * 4 + r;
            const float2 p0 = red[rl][0], p1 = red[rl][1];
            const float mu  = (p0.x + p1.x) * (1.f / 256.f);
            const float ex2 = (p0.y + p1.y) * (1.f / 256.f);
            const float rstd = rsqrtf(fmaxf(ex2 - mu * mu, 0.f) + 1e-5f);
            const size_t row = (size_t)(bm + rl);
#pragma unroll
            for (int j = 0; j < 8; ++j) {
                const int n = wn * 128 + j * 16 + l16;
                Xout[row * 256 + n] = (bf16)((acc[i][j][r] - mu) * rstd * gv[j] + bev[j]);
            }
        }
    }
}

// --------------------------------------------------------------------------
// ffn stage step s (0..63) with per-block hc rotation: hc = ((s>>3)+rot)&7.
//  q<4 : W1 quarter  [128 h][64 k]  8 chunks/row, slot = c ^ (row&7)
//  q>=4: W2 quarter  [256 n][32 k]  paired rows: LDS row = n>>1, 8 slots =
//        ((n&1)*4 + c) ^ ((n>>1)&7)  -> fragment reads 2-way (free)
// --------------------------------------------------------------------------
__device__ __forceinline__ void ffn_stage(int s, int rot, const bf16* __restrict__ W1,
                                          const bf16* __restrict__ W2,
                                          char* buf, int tid)
{
    const int hc = ((s >> 3) + rot) & 7;
    const int q  = s & 7;
    if (q < 4) {
#pragma unroll
        for (int it = 0; it < 4; ++it) {
            const int L = it * 256 + tid;
            const int row = L >> 3, psl = L & 7;
            const int c = psl ^ (row & 7);
            async_copy16(W1 + (size_t)(hc * 128 + row) * 256 + q * 64 + c * 8,
                         buf + (size_t)L * 16);
        }
    } else {
#pragma unroll
        for (int it = 0; it < 4; ++it) {
            const int L = it * 256 + tid;
            const int r128 = L >> 3, psl = L & 7;
            const int g = psl ^ (r128 & 7);
            const int n = r128 * 2 + (g >> 2);
            const int c = g & 3;
            async_copy16(W2 + (size_t)n * 1024 + hc * 128 + (q - 4) * 32 + c * 8,
                         buf + (size_t)L * 16);
        }
    }
}

// --------------------------------------------------------------------------
// Fused FFN (R9): Xout = LN(X + relu(X@W1^T+b1)@W2^T + b2)*gam + bet.
// 64-row tile, grid 1152, 4 waves 2x2. Counted-vmcnt ping-pong, hc rotation.
// LDS: Xs 32K | Ts 16K (red aliases) | stage 2x16K = 80KB -> 2 blocks/CU.
// --------------------------------------------------------------------------
__global__ __launch_bounds__(256, 2) void ffn_fused_k(
    const bf16* __restrict__ X,
    const bf16* __restrict__ W1, const float* __restrict__ b1,
    const bf16* __restrict__ W2, const float* __restrict__ b2,
    const float* __restrict__ gam, const float* __restrict__ bet,
    bf16* __restrict__ Xout)
{
    __shared__ __align__(16) char smem[81920];
    bf16* Xs = (bf16*)smem;                       // 64 x 256 (32 slots/row)
    bf16* Ts = (bf16*)(smem + 32768);             // 64 x 128 (16 slots/row)
    float2 (*red)[2] = (float2 (*)[2])(void*)(smem + 32768);   // aliases Ts
    char* stg = smem + 49152;                     // 2 x 16KB

    const int tid  = threadIdx.x;
    const int lane = tid & 63;
    const int wv   = tid >> 6;
    const int wm   = wv >> 1;
    const int wn   = wv & 1;
    const int quad = lane >> 4;
    const int l16  = lane & 15;
    const int bm   = blockIdx.x * 64;
    const int rot  = (blockIdx.x >> 3) & 7;

#pragma unroll
    for (int it = 0; it < 8; ++it) {
        const int L = it * 256 + tid;
        const int row = L >> 5, slot = L & 31;
        const int gch = (slot & 24) | ((slot ^ row) & 7);
        async_copy16(X + (size_t)(bm + row) * 256 + gch * 8,
                     (char*)Xs + (size_t)L * 16);
    }
    ffn_stage(0, rot, W1, W2, stg, tid);
    ffn_stage(1, rot, W1, W2, stg + 16384, tid);

    f32x4 acc2[2][8] = {};

#pragma unroll 1
    for (int hc = 0; hc < 8; ++hc) {
        const int hcr = (hc + rot) & 7;
        float b1v[4];
#pragma unroll
        for (int j = 0; j < 4; ++j)
            b1v[j] = b1[hcr * 128 + wn * 64 + j * 16 + l16];

        f32x4 accA[2][4] = {};

        // ---- phase A: accA = Xs @ W1c^T, 4 steps of 64k
#pragma unroll
        for (int q = 0; q < 4; ++q) {
            const int s = hc * 8 + q;
            const char* cur = stg + (size_t)(q & 1) * 16384;
            ffn_stage(s + 1, rot, W1, W2, stg + (size_t)((q + 1) & 1) * 16384, tid);
            WAITV4_BAR();
#pragma unroll
            for (int kk = 0; kk < 2; ++kk) {
                const int ch = kk * 4 + quad;
                const int gc = q * 8 + ch;
                bf16x8 af[2], bfr[4];
#pragma unroll
                for (int i = 0; i < 2; ++i) {
                    const int m  = wm * 32 + i * 16 + l16;
                    const int sl = (gc & 24) | ((gc ^ m) & 7);
                    af[i] = *(const bf16x8*)((const char*)Xs + (m * 32 + sl) * 16);
                }
#pragma unroll
                for (int j = 0; j < 4; ++j) {
                    const int n  = wn * 64 + j * 16 + l16;
                    const int sl = ch ^ (n & 7);
                    bfr[j] = *(const bf16x8*)(cur + (n * 8 + sl) * 16);
                }
                __builtin_amdgcn_s_setprio(1);
#pragma unroll
                for (int i = 0; i < 2; ++i)
#pragma unroll
                    for (int j = 0; j < 4; ++j)
                        accA[i][j] = __builtin_amdgcn_mfma_f32_16x16x32_bf16(
                            af[i], bfr[j], accA[i][j], 0, 0, 0);
                __builtin_amdgcn_s_setprio(0);
            }
            WAITL_BAR();
        }

        // ---- Ts = relu(accA + b1)
#pragma unroll
        for (int j = 0; j < 4; ++j) {
            const int h  = wn * 64 + j * 16 + l16;
            const float bb = b1v[j];
            const int g  = h >> 3;
#pragma unroll
            for (int i = 0; i < 2; ++i)
#pragma unroll
                for (int r = 0; r < 4; ++r) {
                    const int m  = wm * 32 + i * 16 + quad * 4 + r;
                    const int sl = (g & 8) | ((g ^ m) & 7);
                    const float v = fmaxf(accA[i][j][r] + bb, 0.f);
                    *((bf16*)((char*)Ts + (m * 16 + sl) * 16 + (h & 7) * 2)) = (bf16)v;
                }
        }
        WAITL_BAR();

        // ---- phase B: acc2 += Ts @ W2c^T, 4 steps of 32k
#pragma unroll
        for (int q = 0; q < 4; ++q) {
            const int s = hc * 8 + 4 + q;
            const char* cur = stg + (size_t)(q & 1) * 16384;
            if (s < 63) {
                ffn_stage(s + 1, rot, W1, W2, stg + (size_t)((q + 1) & 1) * 16384, tid);
                WAITV4_BAR();
            } else {
                WAITV0_BAR();
            }
            const int tc = q * 4 + quad;
            bf16x8 af[2], bfr[8];
#pragma unroll
            for (int i = 0; i < 2; ++i) {
                const int m  = wm * 32 + i * 16 + l16;
                const int sl = (tc & 8) | ((tc ^ m) & 7);
                af[i] = *(const bf16x8*)((const char*)Ts + (m * 16 + sl) * 16);
            }
#pragma unroll
            for (int j = 0; j < 8; ++j) {
                const int n  = wn * 128 + j * 16 + l16;
                const int sl = (((n & 1) * 4 + quad) ^ ((n >> 1) & 7)) & 7;
                bfr[j] = *(const bf16x8*)(cur + ((n >> 1) * 8 + sl) * 16);
            }
            __builtin_amdgcn_s_setprio(1);
#pragma unroll
            for (int i = 0; i < 2; ++i)
#pragma unroll
                for (int j = 0; j < 8; ++j)
                    acc2[i][j] = __builtin_amdgcn_mfma_f32_16x16x32_bf16(
                        af[i], bfr[j], acc2[i][j], 0, 0, 0);
            __builtin_amdgcn_s_setprio(0);
            WAITL_BAR();
        }
    }

    // ---- epilogue: bias + residual (from Xs) + LayerNorm
    float bv[8], gv[8], bev[8];
#pragma unroll
    for (int j = 0; j < 8; ++j) {
        const int n = wn * 128 + j * 16 + l16;
        bv[j] = b2[n]; gv[j] = gam[n]; bev[j] = bet[n];
    }

#pragma unroll
    for (int i = 0; i < 2; ++i) {
#pragma unroll
        for (int r = 0; r < 4; ++r) {
            const int rl = wm * 32 + i * 16 + quad * 4 + r;
            float s1 = 0.f, s2 = 0.f;
#pragma unroll
            for (int j = 0; j < 8; ++j) {
                const int n  = wn * 128 + j * 16 + l16;
                const int gc = n >> 3;
                const int sl = (gc & 24) | ((gc ^ rl) & 7);
                const float xr = (float)*((const bf16*)((const char*)Xs +
                                   (rl * 32 + sl) * 16 + (n & 7) * 2));
                const float v = acc2[i][j][r] + bv[j] + xr;
                acc2[i][j][r] = v;
                s1 += v; s2 += v * v;
            }
#pragma unroll
            for (int off = 1; off < 16; off <<= 1) {
                s1 += __shfl_xor(s1, off, 64);
                s2 += __shfl_xor(s2, off, 64);
            }
            if (l16 == 0) red[rl][wn] = make_float2(s1, s2);
        }
    }
    __syncthreads();

#pragma unroll
    for (int i = 0; i < 2; ++i) {
#pragma unroll
        for (int r = 0; r < 4; ++r) {
            const int rl = wm * 32 + i * 16 + quad * 4 + r;
            const float2 p0 = red[rl][0], p1 = red[rl][1];
            const float mu  = (p0.x + p1.x) * (1.f / 256.f);
            const float ex2 = (p0.y + p1.y) * (1.f / 256.f);
            const float rstd = rsqrtf(fmaxf(ex2 - mu * mu, 0.f) + 1e-5f);
            const size_t row = (size_t)(bm + rl);
#pragma unroll
            for (int j = 0; j < 8; ++j) {
                const int n = wn * 128 + j * 16 + l16;
                Xout[row * 256 + n] = (bf16)((acc2[i][j][r] - mu) * rstd * gv[j] + bev[j]);
            }
        }
    }
}

// --------------------------------------------------------------------------
// out[b][c][hw] = sum_e (mean_cam X[p*4+cam][e]) * Wout[c][e] + bout[c]
// --------------------------------------------------------------------------
__global__ __launch_bounds__(256) void out_proj_k(const bf16* __restrict__ X,
                                                  const float* __restrict__ Wout,
                                                  const float* __restrict__ bout,
                                                  float* __restrict__ out)
{
    __shared__ float fused[16][260];
    const int tid = threadIdx.x;
    const int p0  = blockIdx.x * 16;

#pragma unroll
    for (int it = 0; it < 16; ++it) {
        const int idx = it * 256 + tid;
        const int pix = idx >> 8, e = idx & 255;
        const size_t base = (size_t)(p0 + pix) * 1024 + e;
        const float s = (float)X[base] + (float)X[base + 256] +
                        (float)X[base + 512] + (float)X[base + 768];
        fused[pix][e] = s * 0.25f;
    }
    __syncthreads();

    const int pix = tid & 15;
    const int c0  = tid >> 4;
    const int p   = p0 + pix;
    const int b   = p / 9216;
    const int hw  = p % 9216;
#pragma unroll
    for (int it = 0; it < 4; ++it) {
        const int c = it * 16 + c0;
        const float* w = Wout + c * 256;
        float acc = bout[c];
#pragma unroll 8
        for (int e = 0; e < 256; ++e) acc += fused[pix][e] * w[e];
        out[((size_t)b * 64 + c) * 9216 + hw] = acc;
    }
}

// --------------------------------------------------------------------------
extern "C" void kernel_launch(void* const* d_in, const int* in_sizes, int n_in,
                              void* d_out, int out_size, void* d_ws, size_t ws_size,
                              hipStream_t stream)
{
    const float* features = (const float*)d_in[0];
    const float* Wp   = (const float*)d_in[1];
    const float* bp   = (const float*)d_in[2];
    const float* Wqkv = (const float*)d_in[3];
    const float* bqkv = (const float*)d_in[4];
    const float* Wo   = (const float*)d_in[5];
    const float* bo   = (const float*)d_in[6];
    const float* W1   = (const float*)d_in[7];
    const float* b1   = (const float*)d_in[8];
    const float* W2   = (const float*)d_in[9];
    const float* b2   = (const float*)d_in[10];
    const float* g1   = (const float*)d_in[11];
    const float* be1  = (const float*)d_in[12];
    const float* g2   = (const float*)d_in[13];
    const float* be2  = (const float*)d_in[14];
    const float* Wout = (const float*)d_in[15];
    const float* bout = (const float*)d_in[16];
    float* out = (float*)d_out;

    char* ws = (char*)d_ws;
    bf16* X   = (bf16*)(ws);                    // 73728*256
    bf16* QKV = (bf16*)(ws + 37748736ull);      // 73728*768
    bf16* Xf  = (bf16*)(ws + 188743680ull);     // 73728*64
    bf16* WpB = (bf16*)(ws + 198180864ull);     // 256*64
    bf16* Wb  = (bf16*)(ws + 226492416ull);     // packed bf16 weights

    bf16* WqkvB = Wb;                  // 2 x 768*256
    bf16* WoB   = Wb + 393216;         // 2 x 256*256
    bf16* W1B   = Wb + 524288;         // 2 x 1024*256
    bf16* W2B   = Wb + 1048576;        // 2 x 256*1024

    pack_all_k<<<6208, 256, 0, stream>>>(Wqkv, Wo, W1, W2, Wp,
                                         WqkvB, WoB, W1B, W2B, WpB);

    feat_pack_k<<<dim3(144, 8), 256, 0, stream>>>(features, Xf);
    gemm_bt<false><<<dim3(2, 576), 256, 0, stream>>>(Xf, WpB, bp, X, 256, 64);

    for (int l = 0; l < 2; ++l) {
        gemm_bt<false><<<dim3(6, 576), 256, 0, stream>>>(
            X, WqkvB + l * 196608, bqkv + l * 768, QKV, 768, 256);
        attn_ln_k<<<1152, 256, 0, stream>>>(
            QKV, WoB + l * 65536, bo + l * 256, X,
            g1 + l * 256, be1 + l * 256, X);
        ffn_fused_k<<<1152, 256, 0, stream>>>(
            X, W1B + l * 262144, b1 + l * 1024,
            W2B + l * 262144, b2 + l * 256,
            g2 + l * 256, be2 + l * 256, X);
    }

    out_proj_k<<<1152, 256, 0, stream>>>(X, Wout, bout, out);
}